// Round 12
// baseline (174.900 us; speedup 1.0000x reference)
//
#include <hip/hip_runtime.h>

#define N_ATOMS 32768
#define E_EDGES 524288
#define FEAT 32
#define TPB 1024
#define WPB 16
#define PASSES 4
#define GRID (E_EDGES / (WPB * PASSES * 16))   // 512 blocks = 2/CU
#define INV_SQRT3 0.57735026919f
#define MSG_SCALE 0.0625f         // ALPHA (0.25) / sqrt(AVG_NEI) (4)
#define SELF_SCALE 0.35355339059f // 1/sqrt(8)

// ---- workspace layout (bytes) ----
#define WS_MSG   0                         // f16 msg [E][32]  = 33,554,432 B
#define WS_CNT   33554432                  // int [32768]
#define WS_CUR   33685504                  // int [32768]   (cnt+cur zeroed together)
#define WS_OFFS  33816576                  // int [32768]
#define WS_BSUM  33947648                  // int [128]
#define WS_BBASE 33948160                  // int [128]
#define WS_EIDS  33948672                  // int [E] (2 MB)
#define WS_WF    36045824                  // f16 frags: w1 2048, w2 4096, w3 16384 elems

typedef _Float16 f16;
typedef __attribute__((ext_vector_type(8))) _Float16 f16x8;
typedef __attribute__((ext_vector_type(4))) float f32x4;
typedef __attribute__((ext_vector_type(2))) _Float16 f16x2;
typedef __attribute__((ext_vector_type(4))) _Float16 f16x4;

__device__ __forceinline__ float silu(float x) { return x / (1.0f + __expf(-x)); }

__device__ __forceinline__ f32x4 mfma16(f16x8 a, f16x8 b, f32x4 c) {
    return __builtin_amdgcn_mfma_f32_16x16x32_f16(a, b, c, 0, 0, 0);
}

// ---------------- weight fragment pre-arrangement ----------------
// B-fragment layout: frag[(kk*NT+n0)*64 + lane][j] = W[k][n],
// k = kk*32 + (lane>>4)*8 + j,  n = n0*16 + (lane&15)
__global__ __launch_bounds__(256) void prep_kernel(
    const float* __restrict__ W1, const float* __restrict__ W2,
    const float* __restrict__ W3, f16* __restrict__ wf)
{
    int idx = blockIdx.x * 256 + threadIdx.x;   // 0 .. 22527
    float v;
    if (idx < 2048) {
        int f = idx;
        int n0 = f >> 9, lane = (f >> 3) & 63, j = f & 7;
        int k = ((lane >> 4) << 3) + j, n = (n0 << 4) + (lane & 15);
        v = (k < 8) ? W1[k * 64 + n] : 0.0f;
    } else if (idx < 6144) {
        int f = idx - 2048;
        int kk = f >> 11, n0 = (f >> 9) & 3, lane = (f >> 3) & 63, j = f & 7;
        int k = (kk << 5) + ((lane >> 4) << 3) + j, n = (n0 << 4) + (lane & 15);
        v = W2[k * 64 + n];
    } else {
        int f = idx - 6144;
        int kk = f >> 13, n0 = (f >> 9) & 15, lane = (f >> 3) & 63, j = f & 7;
        int k = (kk << 5) + ((lane >> 4) << 3) + j, n = (n0 << 4) + (lane & 15);
        v = W3[k * 256 + n];
    }
    wf[idx] = (f16)v;
}

// ---------------- CSR build ----------------
__global__ __launch_bounds__(256) void count_kernel(const int* __restrict__ eidx,
                                                    int* __restrict__ cnt) {
    int e = blockIdx.x * 256 + threadIdx.x;
    atomicAdd(&cnt[eidx[E_EDGES + e]], 1);
}

__global__ __launch_bounds__(256) void scan1_kernel(const int* __restrict__ cnt,
                                                    int* __restrict__ bsum) {
    __shared__ int s[256];
    int t = threadIdx.x;
    s[t] = cnt[blockIdx.x * 256 + t];
    __syncthreads();
    for (int d = 128; d > 0; d >>= 1) {
        if (t < d) s[t] += s[t + d];
        __syncthreads();
    }
    if (t == 0) bsum[blockIdx.x] = s[0];
}

__global__ __launch_bounds__(64) void scan2_kernel(const int* __restrict__ bsum,
                                                   int* __restrict__ bbase) {
    int lane = threadIdx.x;
    int v0 = bsum[2 * lane], v1 = bsum[2 * lane + 1];
    int s = v0 + v1, x = s;
    for (int d = 1; d < 64; d <<= 1) {
        int y = __shfl_up(x, d, 64);
        if (lane >= d) x += y;
    }
    int excl = x - s;
    bbase[2 * lane] = excl;
    bbase[2 * lane + 1] = excl + v0;
}

__global__ __launch_bounds__(256) void scan3_kernel(const int* __restrict__ cnt,
                                                    const int* __restrict__ bbase,
                                                    int* __restrict__ offs) {
    int t = threadIdx.x, lane = t & 63, w = t >> 6;
    int v = cnt[blockIdx.x * 256 + t];
    int x = v;
    for (int d = 1; d < 64; d <<= 1) {
        int y = __shfl_up(x, d, 64);
        if (lane >= d) x += y;
    }
    __shared__ int wsum[4];
    if (lane == 63) wsum[w] = x;
    __syncthreads();
    int base = bbase[blockIdx.x];
    for (int i = 0; i < w; ++i) base += wsum[i];
    offs[blockIdx.x * 256 + t] = base + x - v;
}

__global__ __launch_bounds__(256) void fill_kernel(const int* __restrict__ eidx,
                                                   const int* __restrict__ offs,
                                                   int* __restrict__ cur,
                                                   int* __restrict__ eids) {
    int e = blockIdx.x * 256 + threadIdx.x;
    int d = eidx[E_EDGES + e];
    int slot = atomicAdd(&cur[d], 1);
    eids[offs[d] + slot] = e;
}

// ---- edge MLP + message: W2+W3 in LDS shared by 16 waves, W1 via L1,
//      double-buffered tpt, coalesced msg write by edge id ----
__global__ __launch_bounds__(TPB, 4) void edge_kernel(
    const float* __restrict__ h, const int* __restrict__ eidx,
    const float* __restrict__ esh, const float* __restrict__ erad,
    const f16* __restrict__ wf,
    const float* __restrict__ b1, const float* __restrict__ b2,
    const float* __restrict__ b3,
    f16* __restrict__ msg)
{
    __shared__ f16x8 w2L[512];                  //  8 KB
    __shared__ f16x8 w3L[2048];                 // 32 KB
    __shared__ float b1s[64], b2s[64], b3s[256];
    // per-wave union: xs [16][72] f16 (2304 B) / tpt [2][16][18] f32 (2304 B)
    __shared__ __align__(16) char xtp[WPB][16 * 72 * 2];  // 36.9 KB

    const int tid = threadIdx.x;
    { // stage W2+W3 fragments to LDS (one-time, 40 KB, vector copies)
        const f16x8* wfW2 = (const f16x8*)(wf + 2048);
        const f16x8* wfW3 = (const f16x8*)(wf + 6144);
        if (tid < 512) w2L[tid] = wfW2[tid];
        w3L[tid] = wfW3[tid];
        w3L[tid + 1024] = wfW3[tid + 1024];
    }
    if (tid < 64) { b1s[tid] = b1[tid]; b2s[tid] = b2[tid]; }
    if (tid < 256) b3s[tid] = b3[tid];
    __syncthreads();

    const f16x8* w1f = (const f16x8*)(wf);      // [4*64] from global (L1-hot)

    const int wave = tid >> 6, lane = tid & 63;
    const int g = lane >> 4, m = lane & 15;        // MFMA fragment coords
    const int me = lane >> 2, w0 = (lane & 3) * 2; // message coords: 4 lanes/edge

    f16* xs = (f16*)&xtp[wave][0];      // [16][72] f16, row stride 144 B
    float* tpt = (float*)&xtp[wave][0]; // [2][16][18] f32

    for (int pass = 0; pass < PASSES; ++pass) {
        const int tile = (blockIdx.x * WPB + wave) * PASSES + pass;
        const int e0 = tile * 16;

        // radial A-fragment (K padded 8->32; only k<8 lanes nonzero)
        f16x8 arad;
        {
            float r[8] = {0.f, 0.f, 0.f, 0.f, 0.f, 0.f, 0.f, 0.f};
            if (g == 0) {
                const float4* rp = (const float4*)(erad + (long)(e0 + m) * 8);
                float4 r0 = rp[0], r1 = rp[1];
                r[0] = r0.x; r[1] = r0.y; r[2] = r0.z; r[3] = r0.w;
                r[4] = r1.x; r[5] = r1.y; r[6] = r1.z; r[7] = r1.w;
            }
#pragma unroll
            for (int j = 0; j < 8; ++j) arad[j] = (f16)r[j];
        }

        // ---- L1: 8 -> 64 (W1 fragments from global, issued up-front) ----
#pragma unroll
        for (int n0 = 0; n0 < 4; ++n0) {
            f32x4 acc = {};
            acc = mfma16(arad, w1f[n0 * 64 + lane], acc);
            float bn = b1s[n0 * 16 + m];
#pragma unroll
            for (int q = 0; q < 4; ++q) {
                float v = silu(acc[q] + bn);
                xs[(g * 4 + q) * 72 + n0 * 16 + m] = (f16)v;
            }
        }
        f16x8 a2[2];
        a2[0] = *(const f16x8*)(xs + m * 72 + g * 8);
        a2[1] = *(const f16x8*)(xs + m * 72 + 32 + g * 8);

        // ---- message-edge loads (post-L1 to cut live range) ----
        const int src = eidx[e0 + me];
        const float4 shv = *(const float4*)(esh + (long)(e0 + me) * 4);
        float hrow[32];
        {
            const float* hp = h + (long)src * FEAT;
#pragma unroll
            for (int c4 = 0; c4 < 8; ++c4)
                ((float4*)hrow)[c4] = ((const float4*)hp)[c4];
        }

        // ---- L2: 64 -> 64 ----
#pragma unroll
        for (int n0 = 0; n0 < 4; ++n0) {
            f32x4 acc = {};
            acc = mfma16(a2[0], w2L[n0 * 64 + lane], acc);
            acc = mfma16(a2[1], w2L[(4 + n0) * 64 + lane], acc);
            float bn = b2s[n0 * 16 + m];
#pragma unroll
            for (int q = 0; q < 4; ++q) {
                float v = silu(acc[q] + bn);
                xs[(g * 4 + q) * 72 + n0 * 16 + m] = (f16)v;
            }
        }
        f16x8 a3[2];
        a3[0] = *(const f16x8*)(xs + m * 72 + g * 8);
        a3[1] = *(const f16x8*)(xs + m * 72 + 32 + g * 8);

        float m0a0 = 0.f, m0a1 = 0.f, s20 = 0.f, s21 = 0.f;
        float sv[6] = {0.f, 0.f, 0.f, 0.f, 0.f, 0.f};

        // ---- L3: 16 tiles (c = t>>2 chunk, n0 = t&3); write buf t&1,
        //      consume tile t-1 from the other buffer (no immediate RTT) ----
#pragma unroll
        for (int t = 0; t < 16; ++t) {
            const int c = t >> 2, n0 = t & 3;
            f32x4 acc = {};
            acc = mfma16(a3[0], w3L[(c * 4 + n0) * 64 + lane], acc);
            acc = mfma16(a3[1], w3L[(16 + c * 4 + n0) * 64 + lane], acc);
            float bn = b3s[c * 64 + n0 * 16 + m];
            float* tb = tpt + (t & 1) * 288;
#pragma unroll
            for (int q = 0; q < 4; ++q)
                tb[(g * 4 + q) * 18 + m] = acc[q] + bn;
            if (t > 0) {
                const int tp = t - 1, cp = tp >> 2, np = tp & 3;
                const float* rb = tpt + (tp & 1) * 288;
#pragma unroll
                for (int uu = 0; uu < 2; ++uu) {
                    const int u = 2 * np + uu;
                    float2 tv = *(const float2*)(rb + me * 18 + uu * 8 + w0);
                    if (cp == 0) {
                        float a0 = hrow[u] * shv.x;
                        m0a0 += a0 * tv.x; m0a1 += a0 * tv.y;
                    } else if (cp == 1) {
                        float a1 = INV_SQRT3 * (hrow[8 + u * 3] * shv.y +
                                                hrow[9 + u * 3] * shv.z +
                                                hrow[10 + u * 3] * shv.w);
                        m0a0 += a1 * tv.x; m0a1 += a1 * tv.y;
                    } else if (cp == 2) {
                        s20 += hrow[u] * tv.x; s21 += hrow[u] * tv.y;
                    } else {
                        sv[0] += hrow[8 + u * 3] * tv.x;
                        sv[1] += hrow[9 + u * 3] * tv.x;
                        sv[2] += hrow[10 + u * 3] * tv.x;
                        sv[3] += hrow[8 + u * 3] * tv.y;
                        sv[4] += hrow[9 + u * 3] * tv.y;
                        sv[5] += hrow[10 + u * 3] * tv.y;
                    }
                }
            }
        }
        { // tail: consume tile 15 (cp=3)
            const float* rb = tpt + 288;
#pragma unroll
            for (int uu = 0; uu < 2; ++uu) {
                const int u = 6 + uu;
                float2 tv = *(const float2*)(rb + me * 18 + uu * 8 + w0);
                sv[0] += hrow[8 + u * 3] * tv.x;
                sv[1] += hrow[9 + u * 3] * tv.x;
                sv[2] += hrow[10 + u * 3] * tv.x;
                sv[3] += hrow[8 + u * 3] * tv.y;
                sv[4] += hrow[9 + u * 3] * tv.y;
                sv[5] += hrow[10 + u * 3] * tv.y;
            }
        }

        // ---- store message slice as f16 (coalesced by edge id) ----
        f16* row = msg + (long)(e0 + me) * FEAT;
        f16x2 p0;
        p0[0] = (f16)(MSG_SCALE * m0a0);
        p0[1] = (f16)(MSG_SCALE * m0a1);
        *(f16x2*)(row + w0) = p0;
        f16 m1v[6];
#pragma unroll
        for (int i = 0; i < 3; ++i) {
            float s1i = (i == 0) ? shv.y : (i == 1) ? shv.z : shv.w;
            m1v[i]     = (f16)(MSG_SCALE * (s1i * s20 + shv.x * sv[i]));
            m1v[3 + i] = (f16)(MSG_SCALE * (s1i * s21 + shv.x * sv[3 + i]));
        }
        f16* rp = row + 8 + 3 * w0;
        { f16x2 t2; t2[0] = m1v[0]; t2[1] = m1v[1]; *(f16x2*)(rp)     = t2; }
        { f16x2 t2; t2[0] = m1v[2]; t2[1] = m1v[3]; *(f16x2*)(rp + 2) = t2; }
        { f16x2 t2; t2[0] = m1v[4]; t2[1] = m1v[5]; *(f16x2*)(rp + 4) = t2; }
    }
}

// ---------------- gather + fused self-interaction ----------------
__global__ __launch_bounds__(256) void gather_kernel(
    const f16* __restrict__ msg, const int* __restrict__ eids,
    const int* __restrict__ offs, const int* __restrict__ cnt,
    const float* __restrict__ h,
    const float* __restrict__ Ws, const float* __restrict__ Wv,
    float* __restrict__ out)
{
    const int t = threadIdx.x;
    const int n = blockIdx.x * 32 + (t >> 3);
    const int L = t & 7;
    const int base = offs[n], deg = cnt[n];

    float a0 = 0.f, a1 = 0.f, a2 = 0.f, a3 = 0.f;
    float c0 = 0.f, c1 = 0.f, c2 = 0.f, c3 = 0.f;
    int i = 0;
    for (; i + 1 < deg; i += 2) {
        int e0 = eids[base + i], e1 = eids[base + i + 1];
        f16x4 v = *(const f16x4*)(msg + (long)e0 * FEAT + L * 4);
        f16x4 w = *(const f16x4*)(msg + (long)e1 * FEAT + L * 4);
        a0 += (float)v[0]; a1 += (float)v[1]; a2 += (float)v[2]; a3 += (float)v[3];
        c0 += (float)w[0]; c1 += (float)w[1]; c2 += (float)w[2]; c3 += (float)w[3];
    }
    if (i < deg) {
        int e0 = eids[base + i];
        f16x4 v = *(const f16x4*)(msg + (long)e0 * FEAT + L * 4);
        a0 += (float)v[0]; a1 += (float)v[1]; a2 += (float)v[2]; a3 += (float)v[3];
    }
    a0 += c0; a1 += c1; a2 += c2; a3 += c3;

    const float* hrow = h + (long)n * FEAT;
    const int f0 = L * 4;
    float o[4];
    if (L < 2) {
#pragma unroll
        for (int j = 0; j < 4; ++j) {
            int w = f0 + j;
            float a = 0.f;
#pragma unroll
            for (int u = 0; u < 8; ++u) a += hrow[u] * Ws[u * 8 + w];
            o[j] = SELF_SCALE * a;
        }
    } else {
#pragma unroll
        for (int j = 0; j < 4; ++j) {
            int f = f0 + j, w = (f - 8) / 3, i3 = (f - 8) % 3;
            float a = 0.f;
#pragma unroll
            for (int u = 0; u < 8; ++u) a += hrow[8 + u * 3 + i3] * Wv[u * 8 + w];
            o[j] = SELF_SCALE * a;
        }
    }
    float4 r;
    r.x = o[0] + a0; r.y = o[1] + a1; r.z = o[2] + a2; r.w = o[3] + a3;
    *(float4*)(out + (long)n * FEAT + f0) = r;
}

extern "C" void kernel_launch(void* const* d_in, const int* in_sizes, int n_in,
                              void* d_out, int out_size, void* d_ws, size_t ws_size,
                              hipStream_t stream)
{
    const float* h    = (const float*)d_in[0];
    const int*   eidx = (const int*)  d_in[1];
    const float* esh  = (const float*)d_in[2];
    const float* erad = (const float*)d_in[3];
    const float* W1   = (const float*)d_in[5];
    const float* b1   = (const float*)d_in[6];
    const float* W2   = (const float*)d_in[7];
    const float* b2   = (const float*)d_in[8];
    const float* W3   = (const float*)d_in[9];
    const float* b3   = (const float*)d_in[10];
    const float* Ws   = (const float*)d_in[11];
    const float* Wv   = (const float*)d_in[12];
    float* out = (float*)d_out;

    char* ws = (char*)d_ws;
    f16* msg   = (f16*)(ws + WS_MSG);
    int* cnt   = (int*)(ws + WS_CNT);
    int* cur   = (int*)(ws + WS_CUR);
    int* offs  = (int*)(ws + WS_OFFS);
    int* bsum  = (int*)(ws + WS_BSUM);
    int* bbase = (int*)(ws + WS_BBASE);
    int* eids  = (int*)(ws + WS_EIDS);
    f16* wf    = (f16*)(ws + WS_WF);

    // zero cnt + cur (adjacent 256 KB)
    hipMemsetAsync(cnt, 0, 2 * N_ATOMS * sizeof(int), stream);

    prep_kernel<<<88, 256, 0, stream>>>(W1, W2, W3, wf);
    count_kernel<<<E_EDGES / 256, 256, 0, stream>>>(eidx, cnt);
    scan1_kernel<<<N_ATOMS / 256, 256, 0, stream>>>(cnt, bsum);
    scan2_kernel<<<1, 64, 0, stream>>>(bsum, bbase);
    scan3_kernel<<<N_ATOMS / 256, 256, 0, stream>>>(cnt, bbase, offs);
    fill_kernel<<<E_EDGES / 256, 256, 0, stream>>>(eidx, offs, cur, eids);
    edge_kernel<<<GRID, TPB, 0, stream>>>(h, eidx, esh, erad, wf,
                                          b1, b2, b3, msg);
    gather_kernel<<<N_ATOMS / 32, 256, 0, stream>>>(msg, eids, offs, cnt,
                                                    h, Ws, Wv, out);
}

// Round 13
// 159.394 us; speedup vs baseline: 1.0973x; 1.0973x over previous
//
#include <hip/hip_runtime.h>

#define N_ATOMS 32768
#define E_EDGES 524288
#define FEAT 32
#define TPB 512
#define WPB 8
#define PASSES 8
#define GRID (E_EDGES / (WPB * PASSES * 16))   // 512 blocks = 2/CU
#define INV_SQRT3 0.57735026919f
#define MSG_SCALE 0.0625f         // ALPHA (0.25) / sqrt(AVG_NEI) (4)
#define SELF_SCALE 0.35355339059f // 1/sqrt(8)

// ---- workspace layout (bytes) ----
#define WS_MSG   0                         // f16 msg [E][32]  = 33,554,432 B
#define WS_CNT   33554432                  // int [32768]
#define WS_CUR   33685504                  // int [32768]   (cnt+cur zeroed together)
#define WS_OFFS  33816576                  // int [32768]
#define WS_BSUM  33947648                  // int [128]
#define WS_BBASE 33948160                  // int [128]
#define WS_EIDS  33948672                  // int [E] (2 MB)
#define WS_WF    36045824                  // f16 frags: w1 2048, w2 4096, w3 16384 elems

typedef _Float16 f16;
typedef __attribute__((ext_vector_type(8))) _Float16 f16x8;
typedef __attribute__((ext_vector_type(4))) float f32x4;
typedef __attribute__((ext_vector_type(2))) _Float16 f16x2;
typedef __attribute__((ext_vector_type(4))) _Float16 f16x4;

__device__ __forceinline__ float silu(float x) { return x / (1.0f + __expf(-x)); }

__device__ __forceinline__ f32x4 mfma16(f16x8 a, f16x8 b, f32x4 c) {
    return __builtin_amdgcn_mfma_f32_16x16x32_f16(a, b, c, 0, 0, 0);
}

// ---------------- weight fragment pre-arrangement ----------------
// B-fragment layout: frag[(kk*NT+n0)*64 + lane][j] = W[k][n],
// k = kk*32 + (lane>>4)*8 + j,  n = n0*16 + (lane&15)
__global__ __launch_bounds__(256) void prep_kernel(
    const float* __restrict__ W1, const float* __restrict__ W2,
    const float* __restrict__ W3, f16* __restrict__ wf)
{
    int idx = blockIdx.x * 256 + threadIdx.x;   // 0 .. 22527
    float v;
    if (idx < 2048) {
        int f = idx;
        int n0 = f >> 9, lane = (f >> 3) & 63, j = f & 7;
        int k = ((lane >> 4) << 3) + j, n = (n0 << 4) + (lane & 15);
        v = (k < 8) ? W1[k * 64 + n] : 0.0f;
    } else if (idx < 6144) {
        int f = idx - 2048;
        int kk = f >> 11, n0 = (f >> 9) & 3, lane = (f >> 3) & 63, j = f & 7;
        int k = (kk << 5) + ((lane >> 4) << 3) + j, n = (n0 << 4) + (lane & 15);
        v = W2[k * 64 + n];
    } else {
        int f = idx - 6144;
        int kk = f >> 13, n0 = (f >> 9) & 15, lane = (f >> 3) & 63, j = f & 7;
        int k = (kk << 5) + ((lane >> 4) << 3) + j, n = (n0 << 4) + (lane & 15);
        v = W3[k * 256 + n];
    }
    wf[idx] = (f16)v;
}

// ---------------- CSR build ----------------
__global__ __launch_bounds__(256) void count_kernel(const int* __restrict__ eidx,
                                                    int* __restrict__ cnt) {
    int e = blockIdx.x * 256 + threadIdx.x;
    atomicAdd(&cnt[eidx[E_EDGES + e]], 1);
}

__global__ __launch_bounds__(256) void scan1_kernel(const int* __restrict__ cnt,
                                                    int* __restrict__ bsum) {
    __shared__ int s[256];
    int t = threadIdx.x;
    s[t] = cnt[blockIdx.x * 256 + t];
    __syncthreads();
    for (int d = 128; d > 0; d >>= 1) {
        if (t < d) s[t] += s[t + d];
        __syncthreads();
    }
    if (t == 0) bsum[blockIdx.x] = s[0];
}

__global__ __launch_bounds__(64) void scan2_kernel(const int* __restrict__ bsum,
                                                   int* __restrict__ bbase) {
    int lane = threadIdx.x;
    int v0 = bsum[2 * lane], v1 = bsum[2 * lane + 1];
    int s = v0 + v1, x = s;
    for (int d = 1; d < 64; d <<= 1) {
        int y = __shfl_up(x, d, 64);
        if (lane >= d) x += y;
    }
    int excl = x - s;
    bbase[2 * lane] = excl;
    bbase[2 * lane + 1] = excl + v0;
}

__global__ __launch_bounds__(256) void scan3_kernel(const int* __restrict__ cnt,
                                                    const int* __restrict__ bbase,
                                                    int* __restrict__ offs) {
    int t = threadIdx.x, lane = t & 63, w = t >> 6;
    int v = cnt[blockIdx.x * 256 + t];
    int x = v;
    for (int d = 1; d < 64; d <<= 1) {
        int y = __shfl_up(x, d, 64);
        if (lane >= d) x += y;
    }
    __shared__ int wsum[4];
    if (lane == 63) wsum[w] = x;
    __syncthreads();
    int base = bbase[blockIdx.x];
    for (int i = 0; i < w; ++i) base += wsum[i];
    offs[blockIdx.x * 256 + t] = base + x - v;
}

__global__ __launch_bounds__(256) void fill_kernel(const int* __restrict__ eidx,
                                                   const int* __restrict__ offs,
                                                   int* __restrict__ cur,
                                                   int* __restrict__ eids) {
    int e = blockIdx.x * 256 + threadIdx.x;
    int d = eidx[E_EDGES + e];
    int slot = atomicAdd(&cur[d], 1);
    eids[offs[d] + slot] = e;
}

// ---- edge MLP + message: ALL weights in LDS (vector-staged from wf),
//      double-buffered tpt in L3 (no same-tile LDS round-trip) ----
__global__ __launch_bounds__(TPB, 4) void edge_kernel(
    const float* __restrict__ h, const int* __restrict__ eidx,
    const float* __restrict__ esh, const float* __restrict__ erad,
    const f16* __restrict__ wf,
    const float* __restrict__ b1, const float* __restrict__ b2,
    const float* __restrict__ b3,
    f16* __restrict__ msg)
{
    __shared__ f16x8 wL[2816];                  // 45,056 B: w1|w2|w3 fragments
    __shared__ float b1s[64], b2s[64], b3s[256];
    // per-wave union: xs [16][72] f16 (2304 B) / tpt [2][16][18] f32 (2304 B)
    __shared__ __align__(16) char xtp[WPB][16 * 72 * 2];  // 18,432 B

    const int tid = threadIdx.x;
    { // ---- prologue: vector-stage all weight fragments (16 B/copy) ----
        const f16x8* wfv = (const f16x8*)wf;
#pragma unroll
        for (int i = 0; i < 5; ++i)
            wL[tid + i * TPB] = wfv[tid + i * TPB];
        int i5 = tid + 5 * TPB;
        if (i5 < 2816) wL[i5] = wfv[i5];
        if (tid < 64) { b1s[tid] = b1[tid]; b2s[tid] = b2[tid]; }
        if (tid < 256) b3s[tid] = b3[tid];
    }
    __syncthreads();

    const f16x8* w1f = wL;            // [4*64]
    const f16x8* w2f = wL + 256;      // [2*4*64]
    const f16x8* w3f = wL + 768;      // [2*16*64]

    const int wave = tid >> 6, lane = tid & 63;
    const int g = lane >> 4, m = lane & 15;        // MFMA fragment coords
    const int me = lane >> 2, w0 = (lane & 3) * 2; // message coords: 4 lanes/edge

    f16* xs = (f16*)&xtp[wave][0];      // [16][72] f16, row stride 144 B
    float* tpt = (float*)&xtp[wave][0]; // [2][16][18] f32

    for (int pass = 0; pass < PASSES; ++pass) {
        const int tile = (blockIdx.x * WPB + wave) * PASSES + pass;
        const int e0 = tile * 16;

        // ---- early loads: src/sh for message edge, h[src] row ----
        const int src = eidx[e0 + me];
        const float4 shv = *(const float4*)(esh + (long)(e0 + me) * 4);
        float hrow[32];
        {
            const float* hp = h + (long)src * FEAT;
#pragma unroll
            for (int c4 = 0; c4 < 8; ++c4)
                ((float4*)hrow)[c4] = ((const float4*)hp)[c4];
        }

        // radial A-fragment (K padded 8->32; only k<8 lanes nonzero)
        f16x8 arad;
        {
            float r[8] = {0.f, 0.f, 0.f, 0.f, 0.f, 0.f, 0.f, 0.f};
            if (g == 0) {
                const float4* rp = (const float4*)(erad + (long)(e0 + m) * 8);
                float4 r0 = rp[0], r1 = rp[1];
                r[0] = r0.x; r[1] = r0.y; r[2] = r0.z; r[3] = r0.w;
                r[4] = r1.x; r[5] = r1.y; r[6] = r1.z; r[7] = r1.w;
            }
#pragma unroll
            for (int j = 0; j < 8; ++j) arad[j] = (f16)r[j];
        }

        // ---- L1: 8 -> 64 ----
#pragma unroll
        for (int n0 = 0; n0 < 4; ++n0) {
            f32x4 acc = {};
            acc = mfma16(arad, w1f[n0 * 64 + lane], acc);
            float bn = b1s[n0 * 16 + m];
#pragma unroll
            for (int q = 0; q < 4; ++q) {
                float v = silu(acc[q] + bn);
                xs[(g * 4 + q) * 72 + n0 * 16 + m] = (f16)v;
            }
        }
        f16x8 a2[2];
        a2[0] = *(const f16x8*)(xs + m * 72 + g * 8);
        a2[1] = *(const f16x8*)(xs + m * 72 + 32 + g * 8);

        // ---- L2: 64 -> 64 ----
#pragma unroll
        for (int n0 = 0; n0 < 4; ++n0) {
            f32x4 acc = {};
            acc = mfma16(a2[0], w2f[n0 * 64 + lane], acc);
            acc = mfma16(a2[1], w2f[(4 + n0) * 64 + lane], acc);
            float bn = b2s[n0 * 16 + m];
#pragma unroll
            for (int q = 0; q < 4; ++q) {
                float v = silu(acc[q] + bn);
                xs[(g * 4 + q) * 72 + n0 * 16 + m] = (f16)v;
            }
        }
        f16x8 a3[2];
        a3[0] = *(const f16x8*)(xs + m * 72 + g * 8);
        a3[1] = *(const f16x8*)(xs + m * 72 + 32 + g * 8);

        float m0a0 = 0.f, m0a1 = 0.f, s20 = 0.f, s21 = 0.f;
        float sv[6] = {0.f, 0.f, 0.f, 0.f, 0.f, 0.f};

        // ---- L3: 16 tiles (c = t>>2 chunk, n0 = t&3); write buf t&1,
        //      consume tile t-1 from the other buffer (no immediate RTT) ----
#pragma unroll
        for (int t = 0; t < 16; ++t) {
            const int c = t >> 2, n0 = t & 3;
            f32x4 acc = {};
            acc = mfma16(a3[0], w3f[(c * 4 + n0) * 64 + lane], acc);
            acc = mfma16(a3[1], w3f[(16 + c * 4 + n0) * 64 + lane], acc);
            float bn = b3s[c * 64 + n0 * 16 + m];
            float* tb = tpt + (t & 1) * 288;
#pragma unroll
            for (int q = 0; q < 4; ++q)
                tb[(g * 4 + q) * 18 + m] = acc[q] + bn;
            if (t > 0) {
                const int tp = t - 1, cp = tp >> 2, np = tp & 3;
                const float* rb = tpt + (tp & 1) * 288;
#pragma unroll
                for (int uu = 0; uu < 2; ++uu) {
                    const int u = 2 * np + uu;
                    float2 tv = *(const float2*)(rb + me * 18 + uu * 8 + w0);
                    if (cp == 0) {
                        float a0 = hrow[u] * shv.x;
                        m0a0 += a0 * tv.x; m0a1 += a0 * tv.y;
                    } else if (cp == 1) {
                        float a1 = INV_SQRT3 * (hrow[8 + u * 3] * shv.y +
                                                hrow[9 + u * 3] * shv.z +
                                                hrow[10 + u * 3] * shv.w);
                        m0a0 += a1 * tv.x; m0a1 += a1 * tv.y;
                    } else if (cp == 2) {
                        s20 += hrow[u] * tv.x; s21 += hrow[u] * tv.y;
                    } else {
                        sv[0] += hrow[8 + u * 3] * tv.x;
                        sv[1] += hrow[9 + u * 3] * tv.x;
                        sv[2] += hrow[10 + u * 3] * tv.x;
                        sv[3] += hrow[8 + u * 3] * tv.y;
                        sv[4] += hrow[9 + u * 3] * tv.y;
                        sv[5] += hrow[10 + u * 3] * tv.y;
                    }
                }
            }
        }
        { // tail: consume tile 15 (cp=3)
            const float* rb = tpt + 288;
#pragma unroll
            for (int uu = 0; uu < 2; ++uu) {
                const int u = 6 + uu;
                float2 tv = *(const float2*)(rb + me * 18 + uu * 8 + w0);
                sv[0] += hrow[8 + u * 3] * tv.x;
                sv[1] += hrow[9 + u * 3] * tv.x;
                sv[2] += hrow[10 + u * 3] * tv.x;
                sv[3] += hrow[8 + u * 3] * tv.y;
                sv[4] += hrow[9 + u * 3] * tv.y;
                sv[5] += hrow[10 + u * 3] * tv.y;
            }
        }

        // ---- store message slice as f16 (coalesced by edge id) ----
        f16* row = msg + (long)(e0 + me) * FEAT;
        f16x2 p0;
        p0[0] = (f16)(MSG_SCALE * m0a0);
        p0[1] = (f16)(MSG_SCALE * m0a1);
        *(f16x2*)(row + w0) = p0;
        f16 m1v[6];
#pragma unroll
        for (int i = 0; i < 3; ++i) {
            float s1i = (i == 0) ? shv.y : (i == 1) ? shv.z : shv.w;
            m1v[i]     = (f16)(MSG_SCALE * (s1i * s20 + shv.x * sv[i]));
            m1v[3 + i] = (f16)(MSG_SCALE * (s1i * s21 + shv.x * sv[3 + i]));
        }
        f16* rp = row + 8 + 3 * w0;
        { f16x2 t2; t2[0] = m1v[0]; t2[1] = m1v[1]; *(f16x2*)(rp)     = t2; }
        { f16x2 t2; t2[0] = m1v[2]; t2[1] = m1v[3]; *(f16x2*)(rp + 2) = t2; }
        { f16x2 t2; t2[0] = m1v[4]; t2[1] = m1v[5]; *(f16x2*)(rp + 4) = t2; }
    }
}

// ---------------- gather + fused self-interaction ----------------
__global__ __launch_bounds__(256) void gather_kernel(
    const f16* __restrict__ msg, const int* __restrict__ eids,
    const int* __restrict__ offs, const int* __restrict__ cnt,
    const float* __restrict__ h,
    const float* __restrict__ Ws, const float* __restrict__ Wv,
    float* __restrict__ out)
{
    const int t = threadIdx.x;
    const int n = blockIdx.x * 32 + (t >> 3);
    const int L = t & 7;
    const int base = offs[n], deg = cnt[n];

    float a0 = 0.f, a1 = 0.f, a2 = 0.f, a3 = 0.f;
    float c0 = 0.f, c1 = 0.f, c2 = 0.f, c3 = 0.f;
    int i = 0;
    for (; i + 1 < deg; i += 2) {
        int e0 = eids[base + i], e1 = eids[base + i + 1];
        f16x4 v = *(const f16x4*)(msg + (long)e0 * FEAT + L * 4);
        f16x4 w = *(const f16x4*)(msg + (long)e1 * FEAT + L * 4);
        a0 += (float)v[0]; a1 += (float)v[1]; a2 += (float)v[2]; a3 += (float)v[3];
        c0 += (float)w[0]; c1 += (float)w[1]; c2 += (float)w[2]; c3 += (float)w[3];
    }
    if (i < deg) {
        int e0 = eids[base + i];
        f16x4 v = *(const f16x4*)(msg + (long)e0 * FEAT + L * 4);
        a0 += (float)v[0]; a1 += (float)v[1]; a2 += (float)v[2]; a3 += (float)v[3];
    }
    a0 += c0; a1 += c1; a2 += c2; a3 += c3;

    const float* hrow = h + (long)n * FEAT;
    const int f0 = L * 4;
    float o[4];
    if (L < 2) {
#pragma unroll
        for (int j = 0; j < 4; ++j) {
            int w = f0 + j;
            float a = 0.f;
#pragma unroll
            for (int u = 0; u < 8; ++u) a += hrow[u] * Ws[u * 8 + w];
            o[j] = SELF_SCALE * a;
        }
    } else {
#pragma unroll
        for (int j = 0; j < 4; ++j) {
            int f = f0 + j, w = (f - 8) / 3, i3 = (f - 8) % 3;
            float a = 0.f;
#pragma unroll
            for (int u = 0; u < 8; ++u) a += hrow[8 + u * 3 + i3] * Wv[u * 8 + w];
            o[j] = SELF_SCALE * a;
        }
    }
    float4 r;
    r.x = o[0] + a0; r.y = o[1] + a1; r.z = o[2] + a2; r.w = o[3] + a3;
    *(float4*)(out + (long)n * FEAT + f0) = r;
}

extern "C" void kernel_launch(void* const* d_in, const int* in_sizes, int n_in,
                              void* d_out, int out_size, void* d_ws, size_t ws_size,
                              hipStream_t stream)
{
    const float* h    = (const float*)d_in[0];
    const int*   eidx = (const int*)  d_in[1];
    const float* esh  = (const float*)d_in[2];
    const float* erad = (const float*)d_in[3];
    const float* W1   = (const float*)d_in[5];
    const float* b1   = (const float*)d_in[6];
    const float* W2   = (const float*)d_in[7];
    const float* b2   = (const float*)d_in[8];
    const float* W3   = (const float*)d_in[9];
    const float* b3   = (const float*)d_in[10];
    const float* Ws   = (const float*)d_in[11];
    const float* Wv   = (const float*)d_in[12];
    float* out = (float*)d_out;

    char* ws = (char*)d_ws;
    f16* msg   = (f16*)(ws + WS_MSG);
    int* cnt   = (int*)(ws + WS_CNT);
    int* cur   = (int*)(ws + WS_CUR);
    int* offs  = (int*)(ws + WS_OFFS);
    int* bsum  = (int*)(ws + WS_BSUM);
    int* bbase = (int*)(ws + WS_BBASE);
    int* eids  = (int*)(ws + WS_EIDS);
    f16* wf    = (f16*)(ws + WS_WF);

    // zero cnt + cur (adjacent 256 KB)
    hipMemsetAsync(cnt, 0, 2 * N_ATOMS * sizeof(int), stream);

    prep_kernel<<<88, 256, 0, stream>>>(W1, W2, W3, wf);
    count_kernel<<<E_EDGES / 256, 256, 0, stream>>>(eidx, cnt);
    scan1_kernel<<<N_ATOMS / 256, 256, 0, stream>>>(cnt, bsum);
    scan2_kernel<<<1, 64, 0, stream>>>(bsum, bbase);
    scan3_kernel<<<N_ATOMS / 256, 256, 0, stream>>>(cnt, bbase, offs);
    fill_kernel<<<E_EDGES / 256, 256, 0, stream>>>(eidx, offs, cur, eids);
    edge_kernel<<<GRID, TPB, 0, stream>>>(h, eidx, esh, erad, wf,
                                          b1, b2, b3, msg);
    gather_kernel<<<N_ATOMS / 32, 256, 0, stream>>>(msg, eids, offs, cnt,
                                                    h, Ws, Wv, out);
}

// Round 14
// 158.337 us; speedup vs baseline: 1.1046x; 1.0067x over previous
//
#include <hip/hip_runtime.h>

#define N_ATOMS 32768
#define E_EDGES 524288
#define FEAT 32
#define TPB 512
#define WPB 8
#define PASSES 8
#define GRID (E_EDGES / (WPB * PASSES * 16))   // 512 blocks = 2/CU
#define INV_SQRT3 0.57735026919f
#define MSG_SCALE 0.0625f         // ALPHA (0.25) / sqrt(AVG_NEI) (4)
#define SELF_SCALE 0.35355339059f // 1/sqrt(8)

// ---- workspace layout (bytes) ----
#define WS_MSG   0                         // f16 msg [E][32]  = 33,554,432 B
#define WS_CNT   33554432                  // int [32768]
#define WS_CUR   33685504                  // int [32768]   (cnt+cur zeroed together)
#define WS_OFFS  33816576                  // int [32768]
#define WS_BSUM  33947648                  // int [128]
#define WS_BBASE 33948160                  // int [128]
#define WS_EIDS  33948672                  // int [E] (2 MB)
#define WS_WF    36045824                  // f16 frags: w1 2048, w2 4096, w3 16384 elems

typedef _Float16 f16;
typedef __attribute__((ext_vector_type(8))) _Float16 f16x8;
typedef __attribute__((ext_vector_type(4))) float f32x4;
typedef __attribute__((ext_vector_type(2))) _Float16 f16x2;
typedef __attribute__((ext_vector_type(4))) _Float16 f16x4;

__device__ __forceinline__ float silu(float x) { return x / (1.0f + __expf(-x)); }

__device__ __forceinline__ f32x4 mfma16(f16x8 a, f16x8 b, f32x4 c) {
    return __builtin_amdgcn_mfma_f32_16x16x32_f16(a, b, c, 0, 0, 0);
}

// ---------------- weight fragment pre-arrangement ----------------
// B-fragment layout: frag[(kk*NT+n0)*64 + lane][j] = W[k][n],
// k = kk*32 + (lane>>4)*8 + j,  n = n0*16 + (lane&15)
__global__ __launch_bounds__(256) void prep_kernel(
    const float* __restrict__ W1, const float* __restrict__ W2,
    const float* __restrict__ W3, f16* __restrict__ wf)
{
    int idx = blockIdx.x * 256 + threadIdx.x;   // 0 .. 22527
    float v;
    if (idx < 2048) {
        int f = idx;
        int n0 = f >> 9, lane = (f >> 3) & 63, j = f & 7;
        int k = ((lane >> 4) << 3) + j, n = (n0 << 4) + (lane & 15);
        v = (k < 8) ? W1[k * 64 + n] : 0.0f;
    } else if (idx < 6144) {
        int f = idx - 2048;
        int kk = f >> 11, n0 = (f >> 9) & 3, lane = (f >> 3) & 63, j = f & 7;
        int k = (kk << 5) + ((lane >> 4) << 3) + j, n = (n0 << 4) + (lane & 15);
        v = W2[k * 64 + n];
    } else {
        int f = idx - 6144;
        int kk = f >> 13, n0 = (f >> 9) & 15, lane = (f >> 3) & 63, j = f & 7;
        int k = (kk << 5) + ((lane >> 4) << 3) + j, n = (n0 << 4) + (lane & 15);
        v = W3[k * 256 + n];
    }
    wf[idx] = (f16)v;
}

// ---------------- CSR build ----------------
__global__ __launch_bounds__(256) void count_kernel(const int* __restrict__ eidx,
                                                    int* __restrict__ cnt) {
    int e = blockIdx.x * 256 + threadIdx.x;
    atomicAdd(&cnt[eidx[E_EDGES + e]], 1);
}

__global__ __launch_bounds__(256) void scan1_kernel(const int* __restrict__ cnt,
                                                    int* __restrict__ bsum) {
    __shared__ int s[256];
    int t = threadIdx.x;
    s[t] = cnt[blockIdx.x * 256 + t];
    __syncthreads();
    for (int d = 128; d > 0; d >>= 1) {
        if (t < d) s[t] += s[t + d];
        __syncthreads();
    }
    if (t == 0) bsum[blockIdx.x] = s[0];
}

__global__ __launch_bounds__(64) void scan2_kernel(const int* __restrict__ bsum,
                                                   int* __restrict__ bbase) {
    int lane = threadIdx.x;
    int v0 = bsum[2 * lane], v1 = bsum[2 * lane + 1];
    int s = v0 + v1, x = s;
    for (int d = 1; d < 64; d <<= 1) {
        int y = __shfl_up(x, d, 64);
        if (lane >= d) x += y;
    }
    int excl = x - s;
    bbase[2 * lane] = excl;
    bbase[2 * lane + 1] = excl + v0;
}

__global__ __launch_bounds__(256) void scan3_kernel(const int* __restrict__ cnt,
                                                    const int* __restrict__ bbase,
                                                    int* __restrict__ offs) {
    int t = threadIdx.x, lane = t & 63, w = t >> 6;
    int v = cnt[blockIdx.x * 256 + t];
    int x = v;
    for (int d = 1; d < 64; d <<= 1) {
        int y = __shfl_up(x, d, 64);
        if (lane >= d) x += y;
    }
    __shared__ int wsum[4];
    if (lane == 63) wsum[w] = x;
    __syncthreads();
    int base = bbase[blockIdx.x];
    for (int i = 0; i < w; ++i) base += wsum[i];
    offs[blockIdx.x * 256 + t] = base + x - v;
}

__global__ __launch_bounds__(256) void fill_kernel(const int* __restrict__ eidx,
                                                   const int* __restrict__ offs,
                                                   int* __restrict__ cur,
                                                   int* __restrict__ eids) {
    int e = blockIdx.x * 256 + threadIdx.x;
    int d = eidx[E_EDGES + e];
    int slot = atomicAdd(&cur[d], 1);
    eids[offs[d] + slot] = e;
}

// ---- edge MLP + message: ALL weights in LDS, edges processed in
//      dst-sorted slot order (eids); msg writes coalesced AND dst-grouped ----
__global__ __launch_bounds__(TPB, 4) void edge_kernel(
    const float* __restrict__ h, const int* __restrict__ eidx,
    const float* __restrict__ esh, const float* __restrict__ erad,
    const f16* __restrict__ wf, const int* __restrict__ eids,
    const float* __restrict__ b1, const float* __restrict__ b2,
    const float* __restrict__ b3,
    f16* __restrict__ msg)
{
    __shared__ f16x8 wL[2816];                  // 45,056 B: w1|w2|w3 fragments
    __shared__ float b1s[64], b2s[64], b3s[256];
    // per-wave union: xs [16][72] f16 (2304 B) / tpt [2][16][18] f32 (2304 B)
    __shared__ __align__(16) char xtp[WPB][16 * 72 * 2];  // 18,432 B

    const int tid = threadIdx.x;
    { // ---- prologue: vector-stage all weight fragments (16 B/copy) ----
        const f16x8* wfv = (const f16x8*)wf;
#pragma unroll
        for (int i = 0; i < 5; ++i)
            wL[tid + i * TPB] = wfv[tid + i * TPB];
        int i5 = tid + 5 * TPB;
        if (i5 < 2816) wL[i5] = wfv[i5];
        if (tid < 64) { b1s[tid] = b1[tid]; b2s[tid] = b2[tid]; }
        if (tid < 256) b3s[tid] = b3[tid];
    }
    __syncthreads();

    const f16x8* w1f = wL;            // [4*64]
    const f16x8* w2f = wL + 256;      // [2*4*64]
    const f16x8* w3f = wL + 768;      // [2*16*64]

    const int wave = tid >> 6, lane = tid & 63;
    const int g = lane >> 4, m = lane & 15;        // MFMA fragment coords
    const int me = lane >> 2, w0 = (lane & 3) * 2; // message coords: 4 lanes/edge

    f16* xs = (f16*)&xtp[wave][0];      // [16][72] f16, row stride 144 B
    float* tpt = (float*)&xtp[wave][0]; // [2][16][18] f32

    for (int pass = 0; pass < PASSES; ++pass) {
        const int tile = (blockIdx.x * WPB + wave) * PASSES + pass;
        const int j0 = tile * 16;               // slot base (dst-sorted)

        // ---- slot -> edge id indirection (L2-hot 2 MB table) ----
        const int eidM = eids[j0 + m];          // radial lanes cover 16 edges
        const int eidE = eids[j0 + me];         // message lanes (4-dup)

        // ---- early loads: src/sh for message edge, h[src] row ----
        const int src = eidx[eidE];
        const float4 shv = *(const float4*)(esh + (long)eidE * 4);
        float hrow[32];
        {
            const float* hp = h + (long)src * FEAT;
#pragma unroll
            for (int c4 = 0; c4 < 8; ++c4)
                ((float4*)hrow)[c4] = ((const float4*)hp)[c4];
        }

        // radial A-fragment (K padded 8->32; only k<8 lanes nonzero)
        f16x8 arad;
        {
            float r[8] = {0.f, 0.f, 0.f, 0.f, 0.f, 0.f, 0.f, 0.f};
            if (g == 0) {
                const float4* rp = (const float4*)(erad + (long)eidM * 8);
                float4 r0 = rp[0], r1 = rp[1];
                r[0] = r0.x; r[1] = r0.y; r[2] = r0.z; r[3] = r0.w;
                r[4] = r1.x; r[5] = r1.y; r[6] = r1.z; r[7] = r1.w;
            }
#pragma unroll
            for (int j = 0; j < 8; ++j) arad[j] = (f16)r[j];
        }

        // ---- L1: 8 -> 64 ----
#pragma unroll
        for (int n0 = 0; n0 < 4; ++n0) {
            f32x4 acc = {};
            acc = mfma16(arad, w1f[n0 * 64 + lane], acc);
            float bn = b1s[n0 * 16 + m];
#pragma unroll
            for (int q = 0; q < 4; ++q) {
                float v = silu(acc[q] + bn);
                xs[(g * 4 + q) * 72 + n0 * 16 + m] = (f16)v;
            }
        }
        f16x8 a2[2];
        a2[0] = *(const f16x8*)(xs + m * 72 + g * 8);
        a2[1] = *(const f16x8*)(xs + m * 72 + 32 + g * 8);

        // ---- L2: 64 -> 64 ----
#pragma unroll
        for (int n0 = 0; n0 < 4; ++n0) {
            f32x4 acc = {};
            acc = mfma16(a2[0], w2f[n0 * 64 + lane], acc);
            acc = mfma16(a2[1], w2f[(4 + n0) * 64 + lane], acc);
            float bn = b2s[n0 * 16 + m];
#pragma unroll
            for (int q = 0; q < 4; ++q) {
                float v = silu(acc[q] + bn);
                xs[(g * 4 + q) * 72 + n0 * 16 + m] = (f16)v;
            }
        }
        f16x8 a3[2];
        a3[0] = *(const f16x8*)(xs + m * 72 + g * 8);
        a3[1] = *(const f16x8*)(xs + m * 72 + 32 + g * 8);

        float m0a0 = 0.f, m0a1 = 0.f, s20 = 0.f, s21 = 0.f;
        float sv[6] = {0.f, 0.f, 0.f, 0.f, 0.f, 0.f};

        // ---- L3: 16 tiles (c = t>>2 chunk, n0 = t&3); write buf t&1,
        //      consume tile t-1 from the other buffer (no immediate RTT) ----
#pragma unroll
        for (int t = 0; t < 16; ++t) {
            const int c = t >> 2, n0 = t & 3;
            f32x4 acc = {};
            acc = mfma16(a3[0], w3f[(c * 4 + n0) * 64 + lane], acc);
            acc = mfma16(a3[1], w3f[(16 + c * 4 + n0) * 64 + lane], acc);
            float bn = b3s[c * 64 + n0 * 16 + m];
            float* tb = tpt + (t & 1) * 288;
#pragma unroll
            for (int q = 0; q < 4; ++q)
                tb[(g * 4 + q) * 18 + m] = acc[q] + bn;
            if (t > 0) {
                const int tp = t - 1, cp = tp >> 2, np = tp & 3;
                const float* rb = tpt + (tp & 1) * 288;
#pragma unroll
                for (int uu = 0; uu < 2; ++uu) {
                    const int u = 2 * np + uu;
                    float2 tv = *(const float2*)(rb + me * 18 + uu * 8 + w0);
                    if (cp == 0) {
                        float a0 = hrow[u] * shv.x;
                        m0a0 += a0 * tv.x; m0a1 += a0 * tv.y;
                    } else if (cp == 1) {
                        float a1 = INV_SQRT3 * (hrow[8 + u * 3] * shv.y +
                                                hrow[9 + u * 3] * shv.z +
                                                hrow[10 + u * 3] * shv.w);
                        m0a0 += a1 * tv.x; m0a1 += a1 * tv.y;
                    } else if (cp == 2) {
                        s20 += hrow[u] * tv.x; s21 += hrow[u] * tv.y;
                    } else {
                        sv[0] += hrow[8 + u * 3] * tv.x;
                        sv[1] += hrow[9 + u * 3] * tv.x;
                        sv[2] += hrow[10 + u * 3] * tv.x;
                        sv[3] += hrow[8 + u * 3] * tv.y;
                        sv[4] += hrow[9 + u * 3] * tv.y;
                        sv[5] += hrow[10 + u * 3] * tv.y;
                    }
                }
            }
        }
        { // tail: consume tile 15 (cp=3)
            const float* rb = tpt + 288;
#pragma unroll
            for (int uu = 0; uu < 2; ++uu) {
                const int u = 6 + uu;
                float2 tv = *(const float2*)(rb + me * 18 + uu * 8 + w0);
                sv[0] += hrow[8 + u * 3] * tv.x;
                sv[1] += hrow[9 + u * 3] * tv.x;
                sv[2] += hrow[10 + u * 3] * tv.x;
                sv[3] += hrow[8 + u * 3] * tv.y;
                sv[4] += hrow[9 + u * 3] * tv.y;
                sv[5] += hrow[10 + u * 3] * tv.y;
            }
        }

        // ---- store message slice as f16 at slot j0+me (coalesced, sorted) ----
        f16* row = msg + (long)(j0 + me) * FEAT;
        f16x2 p0;
        p0[0] = (f16)(MSG_SCALE * m0a0);
        p0[1] = (f16)(MSG_SCALE * m0a1);
        *(f16x2*)(row + w0) = p0;
        f16 m1v[6];
#pragma unroll
        for (int i = 0; i < 3; ++i) {
            float s1i = (i == 0) ? shv.y : (i == 1) ? shv.z : shv.w;
            m1v[i]     = (f16)(MSG_SCALE * (s1i * s20 + shv.x * sv[i]));
            m1v[3 + i] = (f16)(MSG_SCALE * (s1i * s21 + shv.x * sv[3 + i]));
        }
        f16* rp = row + 8 + 3 * w0;
        { f16x2 t2; t2[0] = m1v[0]; t2[1] = m1v[1]; *(f16x2*)(rp)     = t2; }
        { f16x2 t2; t2[0] = m1v[2]; t2[1] = m1v[3]; *(f16x2*)(rp + 2) = t2; }
        { f16x2 t2; t2[0] = m1v[4]; t2[1] = m1v[5]; *(f16x2*)(rp + 4) = t2; }
    }
}

// ---------------- gather (contiguous rows, no indirection) + self ----
__global__ __launch_bounds__(256) void gather_kernel(
    const f16* __restrict__ msg,
    const int* __restrict__ offs, const int* __restrict__ cnt,
    const float* __restrict__ h,
    const float* __restrict__ Ws, const float* __restrict__ Wv,
    float* __restrict__ out)
{
    const int t = threadIdx.x;
    const int n = blockIdx.x * 32 + (t >> 3);
    const int L = t & 7;
    const int base = offs[n], deg = cnt[n];

    float a0 = 0.f, a1 = 0.f, a2 = 0.f, a3 = 0.f;
    float c0 = 0.f, c1 = 0.f, c2 = 0.f, c3 = 0.f;
    int i = 0;
    for (; i + 1 < deg; i += 2) {
        f16x4 v = *(const f16x4*)(msg + (long)(base + i) * FEAT + L * 4);
        f16x4 w = *(const f16x4*)(msg + (long)(base + i + 1) * FEAT + L * 4);
        a0 += (float)v[0]; a1 += (float)v[1]; a2 += (float)v[2]; a3 += (float)v[3];
        c0 += (float)w[0]; c1 += (float)w[1]; c2 += (float)w[2]; c3 += (float)w[3];
    }
    if (i < deg) {
        f16x4 v = *(const f16x4*)(msg + (long)(base + i) * FEAT + L * 4);
        a0 += (float)v[0]; a1 += (float)v[1]; a2 += (float)v[2]; a3 += (float)v[3];
    }
    a0 += c0; a1 += c1; a2 += c2; a3 += c3;

    const float* hrow = h + (long)n * FEAT;
    const int f0 = L * 4;
    float o[4];
    if (L < 2) {
#pragma unroll
        for (int j = 0; j < 4; ++j) {
            int w = f0 + j;
            float a = 0.f;
#pragma unroll
            for (int u = 0; u < 8; ++u) a += hrow[u] * Ws[u * 8 + w];
            o[j] = SELF_SCALE * a;
        }
    } else {
#pragma unroll
        for (int j = 0; j < 4; ++j) {
            int f = f0 + j, w = (f - 8) / 3, i3 = (f - 8) % 3;
            float a = 0.f;
#pragma unroll
            for (int u = 0; u < 8; ++u) a += hrow[8 + u * 3 + i3] * Wv[u * 8 + w];
            o[j] = SELF_SCALE * a;
        }
    }
    float4 r;
    r.x = o[0] + a0; r.y = o[1] + a1; r.z = o[2] + a2; r.w = o[3] + a3;
    *(float4*)(out + (long)n * FEAT + f0) = r;
}

extern "C" void kernel_launch(void* const* d_in, const int* in_sizes, int n_in,
                              void* d_out, int out_size, void* d_ws, size_t ws_size,
                              hipStream_t stream)
{
    const float* h    = (const float*)d_in[0];
    const int*   eidx = (const int*)  d_in[1];
    const float* esh  = (const float*)d_in[2];
    const float* erad = (const float*)d_in[3];
    const float* W1   = (const float*)d_in[5];
    const float* b1   = (const float*)d_in[6];
    const float* W2   = (const float*)d_in[7];
    const float* b2   = (const float*)d_in[8];
    const float* W3   = (const float*)d_in[9];
    const float* b3   = (const float*)d_in[10];
    const float* Ws   = (const float*)d_in[11];
    const float* Wv   = (const float*)d_in[12];
    float* out = (float*)d_out;

    char* ws = (char*)d_ws;
    f16* msg   = (f16*)(ws + WS_MSG);
    int* cnt   = (int*)(ws + WS_CNT);
    int* cur   = (int*)(ws + WS_CUR);
    int* offs  = (int*)(ws + WS_OFFS);
    int* bsum  = (int*)(ws + WS_BSUM);
    int* bbase = (int*)(ws + WS_BBASE);
    int* eids  = (int*)(ws + WS_EIDS);
    f16* wf    = (f16*)(ws + WS_WF);

    // zero cnt + cur (adjacent 256 KB)
    hipMemsetAsync(cnt, 0, 2 * N_ATOMS * sizeof(int), stream);

    prep_kernel<<<88, 256, 0, stream>>>(W1, W2, W3, wf);
    count_kernel<<<E_EDGES / 256, 256, 0, stream>>>(eidx, cnt);
    scan1_kernel<<<N_ATOMS / 256, 256, 0, stream>>>(cnt, bsum);
    scan2_kernel<<<1, 64, 0, stream>>>(bsum, bbase);
    scan3_kernel<<<N_ATOMS / 256, 256, 0, stream>>>(cnt, bbase, offs);
    fill_kernel<<<E_EDGES / 256, 256, 0, stream>>>(eidx, offs, cur, eids);
    edge_kernel<<<GRID, TPB, 0, stream>>>(h, eidx, esh, erad, wf, eids,
                                          b1, b2, b3, msg);
    gather_kernel<<<N_ATOMS / 32, 256, 0, stream>>>(msg, offs, cnt,
                                                    h, Ws, Wv, out);
}